// Round 1
// baseline (1384.133 us; speedup 1.0000x reference)
//
#include <hip/hip_runtime.h>
#include <hip/hip_bf16.h>
#include <math.h>

#define NNODES 50000
#define NEDGES 500000
#define DIM 128

__device__ __forceinline__ float lrelu(float x) { return x > 0.f ? x : 0.2f * x; }

// ---------------- embed: C[r,:] = X[r,:K] @ W[K,128] + b ; writes emb and final ----------------
template <int K>
__global__ void embed_kernel(const float* __restrict__ X, const float* __restrict__ W,
                             const float* __restrict__ b, float* __restrict__ emb,
                             float* __restrict__ fin, int n) {
    __shared__ float xs[8][K];
    const int j = threadIdx.x;            // 0..127 output channel
    const int row0 = blockIdx.x * 8;
    for (int idx = j; idx < 8 * K; idx += 128) {
        int r = idx / K, k = idx - r * K;
        int rr = row0 + r;
        xs[r][k] = (rr < n) ? X[rr * K + k] : 0.f;
    }
    __syncthreads();
    float acc[8];
#pragma unroll
    for (int r = 0; r < 8; r++) acc[r] = 0.f;
    for (int k = 0; k < K; k++) {
        float wv = W[k * 128 + j];
#pragma unroll
        for (int r = 0; r < 8; r++) acc[r] += xs[r][k] * wv;
    }
    float bj = b[j];
#pragma unroll
    for (int r = 0; r < 8; r++) {
        int rr = row0 + r;
        if (rr < n) {
            float v = acc[r] + bj;
            emb[rr * 128 + j] = v;
            fin[rr * 128 + j] = v;
        }
    }
}

// ---------------- xp = H @ Wg (128x128) + per-node attention scores ----------------
__global__ void xp_kernel(const float* __restrict__ Hm, const float* __restrict__ Wg,
                          const float* __restrict__ as_, const float* __restrict__ ad_,
                          float* __restrict__ xp, float* __restrict__ ssrc,
                          float* __restrict__ sdst, int n) {
    __shared__ float xs[8][128];
    const int j = threadIdx.x;
    const int row0 = blockIdx.x * 8;
    for (int idx = j; idx < 8 * 128; idx += 128) {
        int r = idx >> 7, k = idx & 127;
        int rr = row0 + r;
        xs[r][k] = (rr < n) ? Hm[rr * 128 + k] : 0.f;
    }
    __syncthreads();
    float acc[8];
#pragma unroll
    for (int r = 0; r < 8; r++) acc[r] = 0.f;
    for (int k = 0; k < 128; k++) {
        float wv = Wg[k * 128 + j];
#pragma unroll
        for (int r = 0; r < 8; r++) acc[r] += xs[r][k] * wv;
    }
    float asj = as_[j], adj = ad_[j];
#pragma unroll
    for (int r = 0; r < 8; r++) {
        int rr = row0 + r;
        float v = acc[r];
        if (rr < n) xp[rr * 128 + j] = v;
        float ps = v * asj, pd = v * adj;
        // reduce within the 32-lane group (one head = 32 contiguous channels)
        for (int o = 16; o > 0; o >>= 1) {
            ps += __shfl_down(ps, o, 32);
            pd += __shfl_down(pd, o, 32);
        }
        if ((j & 31) == 0 && rr < n) {
            ssrc[rr * 4 + (j >> 5)] = ps;
            sdst[rr * 4 + (j >> 5)] = pd;
        }
    }
}

// ---------------- CSR build ----------------
__global__ void zero_int(int* __restrict__ p, int n) {
    int i = blockIdx.x * blockDim.x + threadIdx.x;
    if (i < n) p[i] = 0;
}

__global__ void count_kernel(const int* __restrict__ dst, int e, int* __restrict__ counts) {
    int i = blockIdx.x * blockDim.x + threadIdx.x;
    if (i < e) atomicAdd(&counts[dst[i]], 1);
}

__global__ void scan_kernel(const int* __restrict__ counts, int* __restrict__ row_ptr,
                            int* __restrict__ cursor, int n) {
    __shared__ int sdata[1024];
    __shared__ int s_running;
    int tid = threadIdx.x;
    if (tid == 0) s_running = 0;
    __syncthreads();
    for (int base = 0; base < n; base += 1024) {
        int i = base + tid;
        int v = (i < n) ? counts[i] : 0;
        sdata[tid] = v;
        __syncthreads();
        for (int off = 1; off < 1024; off <<= 1) {
            int t = (tid >= off) ? sdata[tid - off] : 0;
            __syncthreads();
            sdata[tid] += t;
            __syncthreads();
        }
        int incl = sdata[tid];
        int excl = incl - v;
        int run = s_running;
        if (i < n) {
            row_ptr[i] = run + excl;
            cursor[i] = run + excl;
        }
        __syncthreads();
        if (tid == 1023) s_running = run + incl;
        __syncthreads();
    }
    if (tid == 0) row_ptr[n] = s_running;
}

__global__ void scatter_kernel(const int* __restrict__ src, const int* __restrict__ dst, int e,
                               int* __restrict__ cursor, int* __restrict__ col) {
    int i = blockIdx.x * blockDim.x + threadIdx.x;
    if (i < e) {
        int d = dst[i];
        int p = atomicAdd(&cursor[d], 1);
        col[p] = src[i];
    }
}

// ---------------- dst-centric GAT aggregate: one wave per destination node ----------------
__global__ void gat_aggregate(const float* __restrict__ xp, const float* __restrict__ ssrc,
                              const float* __restrict__ sdst, const int* __restrict__ row_ptr,
                              const int* __restrict__ col, const float* __restrict__ bg,
                              float* __restrict__ fin, int n) {
    const int wave = threadIdx.x >> 6;
    const int lane = threadIdx.x & 63;
    const int i = blockIdx.x * 4 + wave;
    if (i >= n) return;

    float4 sdv = *(const float4*)&sdst[i * 4];
    float4 ssv = *(const float4*)&ssrc[i * 4];
    const float sd0 = sdv.x, sd1 = sdv.y, sd2 = sdv.z, sd3 = sdv.w;
    // self-loop scores
    const float es0 = lrelu(ssv.x + sd0), es1 = lrelu(ssv.y + sd1);
    const float es2 = lrelu(ssv.z + sd2), es3 = lrelu(ssv.w + sd3);

    const int r0 = row_ptr[i], r1 = row_ptr[i + 1];

    // phase 1: max over incoming edges (+self), edge-parallel across lanes
    float m0 = es0, m1 = es1, m2 = es2, m3 = es3;
    for (int k = r0 + lane; k < r1; k += 64) {
        int s = col[k];
        float4 sv = *(const float4*)&ssrc[s * 4];
        m0 = fmaxf(m0, lrelu(sv.x + sd0));
        m1 = fmaxf(m1, lrelu(sv.y + sd1));
        m2 = fmaxf(m2, lrelu(sv.z + sd2));
        m3 = fmaxf(m3, lrelu(sv.w + sd3));
    }
    for (int o = 32; o > 0; o >>= 1) {
        m0 = fmaxf(m0, __shfl_xor(m0, o));
        m1 = fmaxf(m1, __shfl_xor(m1, o));
        m2 = fmaxf(m2, __shfl_xor(m2, o));
        m3 = fmaxf(m3, __shfl_xor(m3, o));
    }

    // phase 2: sum of exp(e - m)
    float t0 = 0.f, t1 = 0.f, t2 = 0.f, t3 = 0.f;
    for (int k = r0 + lane; k < r1; k += 64) {
        int s = col[k];
        float4 sv = *(const float4*)&ssrc[s * 4];
        t0 += expf(lrelu(sv.x + sd0) - m0);
        t1 += expf(lrelu(sv.y + sd1) - m1);
        t2 += expf(lrelu(sv.z + sd2) - m2);
        t3 += expf(lrelu(sv.w + sd3) - m3);
    }
    for (int o = 32; o > 0; o >>= 1) {
        t0 += __shfl_xor(t0, o);
        t1 += __shfl_xor(t1, o);
        t2 += __shfl_xor(t2, o);
        t3 += __shfl_xor(t3, o);
    }
    t0 += expf(es0 - m0);
    t1 += expf(es1 - m1);
    t2 += expf(es2 - m2);
    t3 += expf(es3 - m3);
    const float i0 = 1.f / t0, i1 = 1.f / t1, i2 = 1.f / t2, i3 = 1.f / t3;

    // phase 3: weighted gather, channel-parallel (2 channels/lane)
    const int c = lane * 2;
    const int hh = lane >> 4;  // head of channel c
    const float mh = (hh & 2) ? ((hh & 1) ? m3 : m2) : ((hh & 1) ? m1 : m0);
    const float ih = (hh & 2) ? ((hh & 1) ? i3 : i2) : ((hh & 1) ? i1 : i0);
    const float sdh = (hh & 2) ? ((hh & 1) ? sd3 : sd2) : ((hh & 1) ? sd1 : sd0);
    const float esh = (hh & 2) ? ((hh & 1) ? es3 : es2) : ((hh & 1) ? es1 : es0);

    float2 acc = {0.f, 0.f};
    for (int k = r0; k < r1; k++) {
        int s = col[k];
        float al = expf(lrelu(ssrc[s * 4 + hh] + sdh) - mh) * ih;
        float2 v = *(const float2*)&xp[s * 128 + c];
        acc.x += al * v.x;
        acc.y += al * v.y;
    }
    {   // self-loop
        float al = expf(esh - mh) * ih;
        float2 v = *(const float2*)&xp[i * 128 + c];
        acc.x += al * v.x;
        acc.y += al * v.y;
    }
    float2 f = *(float2*)&fin[i * 128 + c];
    f.x += acc.x + bg[c];
    f.y += acc.y + bg[c + 1];
    *(float2*)&fin[i * 128 + c] = f;
}

// ---------------- classifier: sigmoid(final @ W_cls + b) ----------------
__global__ void classifier_kernel(const float* __restrict__ fin, const float* __restrict__ Wc,
                                  const float* __restrict__ bc, float* __restrict__ out, int rows) {
    const int wave = threadIdx.x >> 6;
    const int lane = threadIdx.x & 63;
    const int r = blockIdx.x * 4 + wave;
    if (r >= rows) return;
    float2 w = *(const float2*)&Wc[lane * 2];
    float2 v = *(const float2*)&fin[r * 128 + lane * 2];
    float p = v.x * w.x + v.y * w.y;
    for (int o = 32; o > 0; o >>= 1) p += __shfl_xor(p, o);
    if (lane == 0) out[r] = 1.f / (1.f + expf(-(p + bc[0])));
}

extern "C" void kernel_launch(void* const* d_in, const int* in_sizes, int n_in,
                              void* d_out, int out_size, void* d_ws, size_t ws_size,
                              hipStream_t stream) {
    const int N = NNODES, E = NEDGES;
    const float* x_acc = (const float*)d_in[0];
    const float* x_cus = (const float*)d_in[1];
    const float* x_txn = (const float*)d_in[2];
    const int* ei_owns = (const int*)d_in[4];
    const int* ei_shr = (const int*)d_in[5];
    const float* W_acc = (const float*)d_in[6];
    const float* b_acc = (const float*)d_in[7];
    const float* W_cus = (const float*)d_in[8];
    const float* b_cus = (const float*)d_in[9];
    const float* W_txn = (const float*)d_in[10];
    const float* b_txn = (const float*)d_in[11];
    const float* Wg_o = (const float*)d_in[12];
    const float* as_o = (const float*)d_in[13];
    const float* ad_o = (const float*)d_in[14];
    const float* bg_o = (const float*)d_in[15];
    const float* Wg_s = (const float*)d_in[16];
    const float* as_s = (const float*)d_in[17];
    const float* ad_s = (const float*)d_in[18];
    const float* bg_s = (const float*)d_in[19];
    const float* W_cls = (const float*)d_in[20];
    const float* b_cls = (const float*)d_in[21];
    float* out = (float*)d_out;

    float* wf = (float*)d_ws;
    // float-offset layout
    float* emb = wf;                              // 3*N*128
    float* fin = wf + 19200000;                   // 3*N*128
    float* xp = wf + 38400000;                    // N*128
    float* ssrc = wf + 44800000;                  // N*4
    float* sdst = wf + 45000000;                  // N*4
    int* iw = (int*)d_ws;
    int* rp_o = iw + 45200000;                    // N+1
    int* rp_s = iw + 45250004;                    // N+1
    int* col_o = iw + 45300008;                   // E
    int* col_s = iw + 45800008;                   // E
    int* counts = iw + 46300008;                  // N
    int* cursor = iw + 46350008;                  // N

    const int gN8 = (N + 7) / 8;
    // 1) embeddings (also initialize final = emb)
    embed_kernel<64><<<gN8, 128, 0, stream>>>(x_acc, W_acc, b_acc, emb, fin, N);
    embed_kernel<32><<<gN8, 128, 0, stream>>>(x_cus, W_cus, b_cus, emb + N * 128, fin + N * 128, N);
    embed_kernel<128><<<gN8, 128, 0, stream>>>(x_txn, W_txn, b_txn, emb + 2 * N * 128, fin + 2 * N * 128, N);

    // 2) CSR for the two live edge types (src = row 0, dst = row 1)
    const int gE = (E + 255) / 256, gN = (N + 255) / 256;
    // owns
    zero_int<<<gN, 256, 0, stream>>>(counts, N);
    count_kernel<<<gE, 256, 0, stream>>>(ei_owns + E, E, counts);
    scan_kernel<<<1, 1024, 0, stream>>>(counts, rp_o, cursor, N);
    scatter_kernel<<<gE, 256, 0, stream>>>(ei_owns, ei_owns + E, E, cursor, col_o);
    // shares
    zero_int<<<gN, 256, 0, stream>>>(counts, N);
    count_kernel<<<gE, 256, 0, stream>>>(ei_shr + E, E, counts);
    scan_kernel<<<1, 1024, 0, stream>>>(counts, rp_s, cursor, N);
    scatter_kernel<<<gE, 256, 0, stream>>>(ei_shr, ei_shr + E, E, cursor, col_s);

    // 3) six GAT evaluations: (conv in {owns, shares}) x (type in {0,1,2})
    const int gAgg = (N + 3) / 4;
    for (int t = 0; t < 3; t++) {
        float* h = emb + (size_t)t * N * 128;
        float* f = fin + (size_t)t * N * 128;
        // owns
        xp_kernel<<<gN8, 128, 0, stream>>>(h, Wg_o, as_o, ad_o, xp, ssrc, sdst, N);
        gat_aggregate<<<gAgg, 256, 0, stream>>>(xp, ssrc, sdst, rp_o, col_o, bg_o, f, N);
        // shares
        xp_kernel<<<gN8, 128, 0, stream>>>(h, Wg_s, as_s, ad_s, xp, ssrc, sdst, N);
        gat_aggregate<<<gAgg, 256, 0, stream>>>(xp, ssrc, sdst, rp_s, col_s, bg_s, f, N);
    }

    // 4) classifier over concatenated rows
    const int rows = 3 * N;
    classifier_kernel<<<(rows + 3) / 4, 256, 0, stream>>>(fin, W_cls, b_cls, out, rows);
}

// Round 2
// 836.767 us; speedup vs baseline: 1.6541x; 1.6541x over previous
//
#include <hip/hip_runtime.h>
#include <hip/hip_bf16.h>
#include <math.h>

#define NNODES 50000
#define NEDGES 500000

__device__ __forceinline__ float lrelu(float x) { return x > 0.f ? x : 0.2f * x; }

__device__ __forceinline__ unsigned short f2bf(float f) {
    unsigned int u = __float_as_uint(f);
    u += 0x7FFFu + ((u >> 16) & 1u);   // round-nearest-even
    return (unsigned short)(u >> 16);
}

// ============ per-type fused kernel: embed GEMM -> h ; h@WgO, h@WgS ; att scores ============
// Tile: 32 rows x 128 cols, 256 threads. j4 = t&31 (col quad), r = t>>5 (row, +8p).
template <int K>
__launch_bounds__(256)
__global__ void xp_all_kernel(const float* __restrict__ X,
                              const float* __restrict__ Wt, const float* __restrict__ bt,
                              const float* __restrict__ WgO, const float* __restrict__ asO,
                              const float* __restrict__ adO,
                              const float* __restrict__ WgS, const float* __restrict__ asS,
                              const float* __restrict__ adS,
                              float* __restrict__ emb,
                              unsigned short* __restrict__ xpO, unsigned short* __restrict__ xpS,
                              float* __restrict__ ssO, float* __restrict__ sdO,
                              float* __restrict__ ssS, float* __restrict__ sdS, int n) {
    __shared__ float xs[32][K];
    __shared__ float hs[32][128];
    const int t = threadIdx.x;
    const int j4 = t & 31, r = t >> 5;
    const int row0 = blockIdx.x * 32;

    constexpr int KQ = K / 4;
    for (int f = t; f < 32 * KQ; f += 256) {
        int row = f / KQ, kq = f - row * KQ;
        float4 v = {0.f, 0.f, 0.f, 0.f};
        if (row0 + row < n) v = *(const float4*)&X[(size_t)(row0 + row) * K + kq * 4];
        *(float4*)&xs[row][kq * 4] = v;
    }
    __syncthreads();

    // GEMM1: h = X @ Wt + bt
    float4 h[4];
#pragma unroll
    for (int p = 0; p < 4; p++) h[p] = {0.f, 0.f, 0.f, 0.f};
#pragma unroll 4
    for (int k = 0; k < K; k++) {
        float4 w = *(const float4*)&Wt[k * 128 + j4 * 4];
        float x0 = xs[r][k], x1 = xs[r + 8][k], x2 = xs[r + 16][k], x3 = xs[r + 24][k];
        h[0].x += x0 * w.x; h[0].y += x0 * w.y; h[0].z += x0 * w.z; h[0].w += x0 * w.w;
        h[1].x += x1 * w.x; h[1].y += x1 * w.y; h[1].z += x1 * w.z; h[1].w += x1 * w.w;
        h[2].x += x2 * w.x; h[2].y += x2 * w.y; h[2].z += x2 * w.z; h[2].w += x2 * w.w;
        h[3].x += x3 * w.x; h[3].y += x3 * w.y; h[3].z += x3 * w.z; h[3].w += x3 * w.w;
    }
    float4 bv = *(const float4*)&bt[j4 * 4];
#pragma unroll
    for (int p = 0; p < 4; p++) {
        h[p].x += bv.x; h[p].y += bv.y; h[p].z += bv.z; h[p].w += bv.w;
        int row = row0 + r + 8 * p;
        *(float4*)&hs[r + 8 * p][j4 * 4] = h[p];
        if (row < n) *(float4*)&emb[(size_t)row * 128 + j4 * 4] = h[p];
    }
    __syncthreads();

    // GEMM2: xpO = h @ WgO, xpS = h @ WgS
    float4 aO[4], aS[4];
#pragma unroll
    for (int p = 0; p < 4; p++) { aO[p] = {0.f, 0.f, 0.f, 0.f}; aS[p] = {0.f, 0.f, 0.f, 0.f}; }
#pragma unroll 2
    for (int k = 0; k < 128; k++) {
        float4 wo = *(const float4*)&WgO[k * 128 + j4 * 4];
        float4 ws = *(const float4*)&WgS[k * 128 + j4 * 4];
        float x0 = hs[r][k], x1 = hs[r + 8][k], x2 = hs[r + 16][k], x3 = hs[r + 24][k];
        aO[0].x += x0 * wo.x; aO[0].y += x0 * wo.y; aO[0].z += x0 * wo.z; aO[0].w += x0 * wo.w;
        aO[1].x += x1 * wo.x; aO[1].y += x1 * wo.y; aO[1].z += x1 * wo.z; aO[1].w += x1 * wo.w;
        aO[2].x += x2 * wo.x; aO[2].y += x2 * wo.y; aO[2].z += x2 * wo.z; aO[2].w += x2 * wo.w;
        aO[3].x += x3 * wo.x; aO[3].y += x3 * wo.y; aO[3].z += x3 * wo.z; aO[3].w += x3 * wo.w;
        aS[0].x += x0 * ws.x; aS[0].y += x0 * ws.y; aS[0].z += x0 * ws.z; aS[0].w += x0 * ws.w;
        aS[1].x += x1 * ws.x; aS[1].y += x1 * ws.y; aS[1].z += x1 * ws.z; aS[1].w += x1 * ws.w;
        aS[2].x += x2 * ws.x; aS[2].y += x2 * ws.y; aS[2].z += x2 * ws.z; aS[2].w += x2 * ws.w;
        aS[3].x += x3 * ws.x; aS[3].y += x3 * ws.y; aS[3].z += x3 * ws.z; aS[3].w += x3 * ws.w;
    }

    float4 vasO = *(const float4*)&asO[j4 * 4];
    float4 vadO = *(const float4*)&adO[j4 * 4];
    float4 vasS = *(const float4*)&asS[j4 * 4];
    float4 vadS = *(const float4*)&adS[j4 * 4];
#pragma unroll
    for (int p = 0; p < 4; p++) {
        int row = row0 + r + 8 * p;
        if (row < n) {
            ushort4 uo, us;
            uo.x = f2bf(aO[p].x); uo.y = f2bf(aO[p].y); uo.z = f2bf(aO[p].z); uo.w = f2bf(aO[p].w);
            us.x = f2bf(aS[p].x); us.y = f2bf(aS[p].y); us.z = f2bf(aS[p].z); us.w = f2bf(aS[p].w);
            *(ushort4*)&xpO[(size_t)row * 128 + j4 * 4] = uo;
            *(ushort4*)&xpS[(size_t)row * 128 + j4 * 4] = us;
        }
        float psO = aO[p].x * vasO.x + aO[p].y * vasO.y + aO[p].z * vasO.z + aO[p].w * vasO.w;
        float pdO = aO[p].x * vadO.x + aO[p].y * vadO.y + aO[p].z * vadO.z + aO[p].w * vadO.w;
        float psS = aS[p].x * vasS.x + aS[p].y * vasS.y + aS[p].z * vasS.z + aS[p].w * vasS.w;
        float pdS = aS[p].x * vadS.x + aS[p].y * vadS.y + aS[p].z * vadS.z + aS[p].w * vadS.w;
#pragma unroll
        for (int o = 4; o > 0; o >>= 1) {
            psO += __shfl_xor(psO, o);
            pdO += __shfl_xor(pdO, o);
            psS += __shfl_xor(psS, o);
            pdS += __shfl_xor(pdS, o);
        }
        if ((j4 & 7) == 0 && row < n) {
            int hidx = row * 4 + (j4 >> 3);
            ssO[hidx] = psO; sdO[hidx] = pdO;
            ssS[hidx] = psS; sdS[hidx] = pdS;
        }
    }
}

// ============ CSR build ============
__global__ void zero_int(int* __restrict__ p, int n) {
    int i = blockIdx.x * blockDim.x + threadIdx.x;
    if (i < n) p[i] = 0;
}

__global__ void count_kernel(const int* __restrict__ dst, int e, int* __restrict__ counts) {
    int i = blockIdx.x * blockDim.x + threadIdx.x;
    if (i < e) atomicAdd(&counts[dst[i]], 1);
}

__global__ void scan_kernel(const int* __restrict__ counts, int* __restrict__ row_ptr,
                            int* __restrict__ cursor, int n) {
    __shared__ int wsum[16];
    __shared__ int s_carry;
    const int tid = threadIdx.x;           // 1024
    const int lane = tid & 63, wid = tid >> 6;
    if (tid == 0) s_carry = 0;
    __syncthreads();
    for (int base = 0; base < n; base += 1024) {
        int i = base + tid;
        int v = (i < n) ? counts[i] : 0;
        int x = v;
#pragma unroll
        for (int o = 1; o < 64; o <<= 1) {
            int tt = __shfl_up(x, o);
            if (lane >= o) x += tt;
        }
        if (lane == 63) wsum[wid] = x;
        __syncthreads();
        if (wid == 0) {
            int ws = (lane < 16) ? wsum[lane] : 0;
#pragma unroll
            for (int o = 1; o < 16; o <<= 1) {
                int tt = __shfl_up(ws, o);
                if (lane >= o) ws += tt;
            }
            if (lane < 16) wsum[lane] = ws;   // inclusive wave-sum scan
        }
        __syncthreads();
        int wave_excl = (wid == 0) ? 0 : wsum[wid - 1];
        int carry = s_carry;
        int excl = carry + wave_excl + x - v;
        if (i < n) { row_ptr[i] = excl; cursor[i] = excl; }
        __syncthreads();
        if (tid == 1023) s_carry = carry + wsum[15];
    }
    __syncthreads();
    if (tid == 0) row_ptr[n] = s_carry;
}

__global__ void scatter_kernel(const int* __restrict__ src, const int* __restrict__ dst, int e,
                               int* __restrict__ cursor, int* __restrict__ col) {
    int i = blockIdx.x * blockDim.x + threadIdx.x;
    if (i < e) {
        int d = dst[i];
        int p = atomicAdd(&cursor[d], 1);
        col[p] = src[i];
    }
}

// ============ aggregate: one wave per destination node, both convs + residual + classifier ============
__device__ __forceinline__ void agg_one(const unsigned short* __restrict__ xp,
                                        const float* __restrict__ ssrc,
                                        const float* __restrict__ sdst,
                                        const int* __restrict__ rp, const int* __restrict__ col,
                                        int i, int lane, int c, int hh, float& ax, float& ay) {
    float4 sdv = *(const float4*)&sdst[i * 4];
    float4 ssv = *(const float4*)&ssrc[i * 4];
    // self-loop scores are the softmax shift (shift-invariant; args stay bounded)
    const float m0 = lrelu(ssv.x + sdv.x), m1 = lrelu(ssv.y + sdv.y);
    const float m2 = lrelu(ssv.z + sdv.z), m3 = lrelu(ssv.w + sdv.w);
    const int r0 = rp[i], r1 = rp[i + 1];

    float t0 = 0.f, t1 = 0.f, t2 = 0.f, t3 = 0.f;
    for (int k = r0 + lane; k < r1; k += 64) {
        int s = col[k];
        float4 sv = *(const float4*)&ssrc[s * 4];
        t0 += expf(lrelu(sv.x + sdv.x) - m0);
        t1 += expf(lrelu(sv.y + sdv.y) - m1);
        t2 += expf(lrelu(sv.z + sdv.z) - m2);
        t3 += expf(lrelu(sv.w + sdv.w) - m3);
    }
#pragma unroll
    for (int o = 32; o > 0; o >>= 1) {
        t0 += __shfl_xor(t0, o);
        t1 += __shfl_xor(t1, o);
        t2 += __shfl_xor(t2, o);
        t3 += __shfl_xor(t3, o);
    }
    t0 += 1.f; t1 += 1.f; t2 += 1.f; t3 += 1.f;   // self: exp(es-es)=1
    const float i0 = 1.f / t0, i1 = 1.f / t1, i2 = 1.f / t2, i3 = 1.f / t3;

    const float mh = (hh & 2) ? ((hh & 1) ? m3 : m2) : ((hh & 1) ? m1 : m0);
    const float ih = (hh & 2) ? ((hh & 1) ? i3 : i2) : ((hh & 1) ? i1 : i0);
    const float sdh = (hh & 2) ? ((hh & 1) ? sdv.w : sdv.z) : ((hh & 1) ? sdv.y : sdv.x);

    for (int k = r0; k < r1; k++) {
        int s = col[k];
        float al = expf(lrelu(ssrc[s * 4 + hh] + sdh) - mh) * ih;
        unsigned int u = *(const unsigned int*)&xp[(size_t)s * 128 + c];
        ax += al * __uint_as_float(u << 16);
        ay += al * __uint_as_float(u & 0xFFFF0000u);
    }
    {   // self-loop: alpha = ih
        unsigned int u = *(const unsigned int*)&xp[(size_t)i * 128 + c];
        ax += ih * __uint_as_float(u << 16);
        ay += ih * __uint_as_float(u & 0xFFFF0000u);
    }
}

__global__ void gat_agg2_kernel(const unsigned short* __restrict__ xpO, const float* __restrict__ ssO,
                                const float* __restrict__ sdO, const int* __restrict__ rpO,
                                const int* __restrict__ colO, const float* __restrict__ bgO,
                                const unsigned short* __restrict__ xpS, const float* __restrict__ ssS,
                                const float* __restrict__ sdS, const int* __restrict__ rpS,
                                const int* __restrict__ colS, const float* __restrict__ bgS,
                                const float* __restrict__ emb, const float* __restrict__ Wc,
                                const float* __restrict__ bc, float* __restrict__ out, int n) {
    const int wave = threadIdx.x >> 6, lane = threadIdx.x & 63;
    const int i = blockIdx.x * 4 + wave;
    if (i >= n) return;
    const int c = lane * 2, hh = lane >> 4;

    float ax = 0.f, ay = 0.f;
    agg_one(xpO, ssO, sdO, rpO, colO, i, lane, c, hh, ax, ay);
    agg_one(xpS, ssS, sdS, rpS, colS, i, lane, c, hh, ax, ay);

    float2 e = *(const float2*)&emb[(size_t)i * 128 + c];
    float fx = e.x + ax + bgO[c] + bgS[c];
    float fy = e.y + ay + bgO[c + 1] + bgS[c + 1];

    float2 w = *(const float2*)&Wc[c];
    float p = fx * w.x + fy * w.y;
#pragma unroll
    for (int o = 32; o > 0; o >>= 1) p += __shfl_xor(p, o);
    if (lane == 0) out[i] = 1.f / (1.f + expf(-(p + bc[0])));
}

extern "C" void kernel_launch(void* const* d_in, const int* in_sizes, int n_in,
                              void* d_out, int out_size, void* d_ws, size_t ws_size,
                              hipStream_t stream) {
    const int N = NNODES, E = NEDGES;
    const float* x_acc = (const float*)d_in[0];
    const float* x_cus = (const float*)d_in[1];
    const float* x_txn = (const float*)d_in[2];
    const int* ei_owns = (const int*)d_in[4];
    const int* ei_shr = (const int*)d_in[5];
    const float* W_acc = (const float*)d_in[6];
    const float* b_acc = (const float*)d_in[7];
    const float* W_cus = (const float*)d_in[8];
    const float* b_cus = (const float*)d_in[9];
    const float* W_txn = (const float*)d_in[10];
    const float* b_txn = (const float*)d_in[11];
    const float* Wg_o = (const float*)d_in[12];
    const float* as_o = (const float*)d_in[13];
    const float* ad_o = (const float*)d_in[14];
    const float* bg_o = (const float*)d_in[15];
    const float* Wg_s = (const float*)d_in[16];
    const float* as_s = (const float*)d_in[17];
    const float* ad_s = (const float*)d_in[18];
    const float* bg_s = (const float*)d_in[19];
    const float* W_cls = (const float*)d_in[20];
    const float* b_cls = (const float*)d_in[21];
    float* out = (float*)d_out;

    float* wf = (float*)d_ws;
    int* iw = (int*)d_ws;
    float* emb = wf;                                                // 19,200,000 f
    unsigned short* xp_o = (unsigned short*)(wf + 19200000);        // 6.4M bf16
    unsigned short* xp_s = (unsigned short*)(wf + 22400000);        // 6.4M bf16
    float* ss_o = wf + 25600000;                                    // 200,000 f
    float* sd_o = wf + 25800000;
    float* ss_s = wf + 26000000;
    float* sd_s = wf + 26200000;
    int* rp_o   = iw + 26400000;                                    // N+1
    int* rp_s   = iw + 26450048;
    int* col_o  = iw + 26500096;                                    // E
    int* col_s  = iw + 27000096;
    int* counts = iw + 27500096;                                    // N
    int* cursor = iw + 27550096;

    const int gE = (E + 255) / 256, gN = (N + 255) / 256;
    const int gT = (N + 31) / 32;       // xp_all tiles
    const int gA = (N + 3) / 4;         // aggregate (wave per node)

    // CSR for the two live edge types (src = row 0, dst = row 1)
    zero_int<<<gN, 256, 0, stream>>>(counts, N);
    count_kernel<<<gE, 256, 0, stream>>>(ei_owns + E, E, counts);
    scan_kernel<<<1, 1024, 0, stream>>>(counts, rp_o, cursor, N);
    scatter_kernel<<<gE, 256, 0, stream>>>(ei_owns, ei_owns + E, E, cursor, col_o);
    zero_int<<<gN, 256, 0, stream>>>(counts, N);
    count_kernel<<<gE, 256, 0, stream>>>(ei_shr + E, E, counts);
    scan_kernel<<<1, 1024, 0, stream>>>(counts, rp_s, cursor, N);
    scatter_kernel<<<gE, 256, 0, stream>>>(ei_shr, ei_shr + E, E, cursor, col_s);

    // per type: fused embed+xp+scores, then fused aggregate+residual+classifier
    // type 0: account (K=64)
    xp_all_kernel<64><<<gT, 256, 0, stream>>>(x_acc, W_acc, b_acc, Wg_o, as_o, ad_o,
                                              Wg_s, as_s, ad_s, emb, xp_o, xp_s,
                                              ss_o, sd_o, ss_s, sd_s, N);
    gat_agg2_kernel<<<gA, 256, 0, stream>>>(xp_o, ss_o, sd_o, rp_o, col_o, bg_o,
                                            xp_s, ss_s, sd_s, rp_s, col_s, bg_s,
                                            emb, W_cls, b_cls, out, N);
    // type 1: customer (K=32)
    xp_all_kernel<32><<<gT, 256, 0, stream>>>(x_cus, W_cus, b_cus, Wg_o, as_o, ad_o,
                                              Wg_s, as_s, ad_s, emb, xp_o, xp_s,
                                              ss_o, sd_o, ss_s, sd_s, N);
    gat_agg2_kernel<<<gA, 256, 0, stream>>>(xp_o, ss_o, sd_o, rp_o, col_o, bg_o,
                                            xp_s, ss_s, sd_s, rp_s, col_s, bg_s,
                                            emb, W_cls, b_cls, out + N, N);
    // type 2: transaction (K=128)
    xp_all_kernel<128><<<gT, 256, 0, stream>>>(x_txn, W_txn, b_txn, Wg_o, as_o, ad_o,
                                               Wg_s, as_s, ad_s, emb, xp_o, xp_s,
                                               ss_o, sd_o, ss_s, sd_s, N);
    gat_agg2_kernel<<<gA, 256, 0, stream>>>(xp_o, ss_o, sd_o, rp_o, col_o, bg_o,
                                            xp_s, ss_s, sd_s, rp_s, col_s, bg_s,
                                            emb, W_cls, b_cls, out + 2 * N, N);
}

// Round 7
// 727.999 us; speedup vs baseline: 1.9013x; 1.1494x over previous
//
#include <hip/hip_runtime.h>
#include <hip/hip_bf16.h>
#include <math.h>

#define NNODES 50000
#define NEDGES 500000

__device__ __forceinline__ float lrelu(float x) { return x > 0.f ? x : 0.2f * x; }

__device__ __forceinline__ unsigned short f2bf(float f) {
    unsigned int u = __float_as_uint(f);
    u += 0x7FFFu + ((u >> 16) & 1u);   // round-nearest-even
    return (unsigned short)(u >> 16);
}

// ============ per-type fused kernel: embed GEMM -> h ; h@WgO, h@WgS ; att scores ============
template <int K>
__launch_bounds__(256)
__global__ void xp_all_kernel(const float* __restrict__ X,
                              const float* __restrict__ Wt, const float* __restrict__ bt,
                              const float* __restrict__ WgO, const float* __restrict__ asO,
                              const float* __restrict__ adO,
                              const float* __restrict__ WgS, const float* __restrict__ asS,
                              const float* __restrict__ adS,
                              float* __restrict__ emb,
                              unsigned short* __restrict__ xpO, unsigned short* __restrict__ xpS,
                              float* __restrict__ ssO, float* __restrict__ sdO,
                              float* __restrict__ ssS, float* __restrict__ sdS, int n) {
    __shared__ float xs[32][K];
    __shared__ float hs[32][128];
    const int t = threadIdx.x;
    const int j4 = t & 31, r = t >> 5;
    const int row0 = blockIdx.x * 32;

    constexpr int KQ = K / 4;
    for (int f = t; f < 32 * KQ; f += 256) {
        int row = f / KQ, kq = f - row * KQ;
        float4 v = {0.f, 0.f, 0.f, 0.f};
        if (row0 + row < n) v = *(const float4*)&X[(size_t)(row0 + row) * K + kq * 4];
        *(float4*)&xs[row][kq * 4] = v;
    }
    __syncthreads();

    // GEMM1: h = X @ Wt + bt
    float4 h[4];
#pragma unroll
    for (int p = 0; p < 4; p++) h[p] = {0.f, 0.f, 0.f, 0.f};
#pragma unroll 4
    for (int k = 0; k < K; k++) {
        float4 w = *(const float4*)&Wt[k * 128 + j4 * 4];
        float x0 = xs[r][k], x1 = xs[r + 8][k], x2 = xs[r + 16][k], x3 = xs[r + 24][k];
        h[0].x += x0 * w.x; h[0].y += x0 * w.y; h[0].z += x0 * w.z; h[0].w += x0 * w.w;
        h[1].x += x1 * w.x; h[1].y += x1 * w.y; h[1].z += x1 * w.z; h[1].w += x1 * w.w;
        h[2].x += x2 * w.x; h[2].y += x2 * w.y; h[2].z += x2 * w.z; h[2].w += x2 * w.w;
        h[3].x += x3 * w.x; h[3].y += x3 * w.y; h[3].z += x3 * w.z; h[3].w += x3 * w.w;
    }
    float4 bv = *(const float4*)&bt[j4 * 4];
#pragma unroll
    for (int p = 0; p < 4; p++) {
        h[p].x += bv.x; h[p].y += bv.y; h[p].z += bv.z; h[p].w += bv.w;
        int row = row0 + r + 8 * p;
        *(float4*)&hs[r + 8 * p][j4 * 4] = h[p];
        if (row < n) *(float4*)&emb[(size_t)row * 128 + j4 * 4] = h[p];
    }
    __syncthreads();

    // GEMM2: xpO = h @ WgO, xpS = h @ WgS
    float4 aO[4], aS[4];
#pragma unroll
    for (int p = 0; p < 4; p++) { aO[p] = {0.f, 0.f, 0.f, 0.f}; aS[p] = {0.f, 0.f, 0.f, 0.f}; }
#pragma unroll 2
    for (int k = 0; k < 128; k++) {
        float4 wo = *(const float4*)&WgO[k * 128 + j4 * 4];
        float4 ws = *(const float4*)&WgS[k * 128 + j4 * 4];
        float x0 = hs[r][k], x1 = hs[r + 8][k], x2 = hs[r + 16][k], x3 = hs[r + 24][k];
        aO[0].x += x0 * wo.x; aO[0].y += x0 * wo.y; aO[0].z += x0 * wo.z; aO[0].w += x0 * wo.w;
        aO[1].x += x1 * wo.x; aO[1].y += x1 * wo.y; aO[1].z += x1 * wo.z; aO[1].w += x1 * wo.w;
        aO[2].x += x2 * wo.x; aO[2].y += x2 * wo.y; aO[2].z += x2 * wo.z; aO[2].w += x2 * wo.w;
        aO[3].x += x3 * wo.x; aO[3].y += x3 * wo.y; aO[3].z += x3 * wo.z; aO[3].w += x3 * wo.w;
        aS[0].x += x0 * ws.x; aS[0].y += x0 * ws.y; aS[0].z += x0 * ws.z; aS[0].w += x0 * ws.w;
        aS[1].x += x1 * ws.x; aS[1].y += x1 * ws.y; aS[1].z += x1 * ws.z; aS[1].w += x1 * ws.w;
        aS[2].x += x2 * ws.x; aS[2].y += x2 * ws.y; aS[2].z += x2 * ws.z; aS[2].w += x2 * ws.w;
        aS[3].x += x3 * ws.x; aS[3].y += x3 * ws.y; aS[3].z += x3 * ws.z; aS[3].w += x3 * ws.w;
    }

    float4 vasO = *(const float4*)&asO[j4 * 4];
    float4 vadO = *(const float4*)&adO[j4 * 4];
    float4 vasS = *(const float4*)&asS[j4 * 4];
    float4 vadS = *(const float4*)&adS[j4 * 4];
#pragma unroll
    for (int p = 0; p < 4; p++) {
        int row = row0 + r + 8 * p;
        if (row < n) {
            ushort4 uo, us;
            uo.x = f2bf(aO[p].x); uo.y = f2bf(aO[p].y); uo.z = f2bf(aO[p].z); uo.w = f2bf(aO[p].w);
            us.x = f2bf(aS[p].x); us.y = f2bf(aS[p].y); us.z = f2bf(aS[p].z); us.w = f2bf(aS[p].w);
            *(ushort4*)&xpO[(size_t)row * 128 + j4 * 4] = uo;
            *(ushort4*)&xpS[(size_t)row * 128 + j4 * 4] = us;
        }
        float psO = aO[p].x * vasO.x + aO[p].y * vasO.y + aO[p].z * vasO.z + aO[p].w * vasO.w;
        float pdO = aO[p].x * vadO.x + aO[p].y * vadO.y + aO[p].z * vadO.z + aO[p].w * vadO.w;
        float psS = aS[p].x * vasS.x + aS[p].y * vasS.y + aS[p].z * vasS.z + aS[p].w * vasS.w;
        float pdS = aS[p].x * vadS.x + aS[p].y * vadS.y + aS[p].z * vadS.z + aS[p].w * vadS.w;
#pragma unroll
        for (int o = 4; o > 0; o >>= 1) {
            psO += __shfl_xor(psO, o);
            pdO += __shfl_xor(pdO, o);
            psS += __shfl_xor(psS, o);
            pdS += __shfl_xor(pdS, o);
        }
        if ((j4 & 7) == 0 && row < n) {
            int hidx = row * 4 + (j4 >> 3);
            ssO[hidx] = psO; sdO[hidx] = pdO;
            ssS[hidx] = psS; sdS[hidx] = pdS;
        }
    }
}

// ============ CSR build (R2-proven single-block scan) ============
__global__ void zero_int(int* __restrict__ p, int n) {
    int i = blockIdx.x * blockDim.x + threadIdx.x;
    if (i < n) p[i] = 0;
}

__global__ void count_kernel(const int* __restrict__ dst, int e, int* __restrict__ counts) {
    int i = blockIdx.x * blockDim.x + threadIdx.x;
    if (i < e) atomicAdd(&counts[dst[i]], 1);
}

__global__ void scan_kernel(const int* __restrict__ counts, int* __restrict__ row_ptr,
                            int* __restrict__ cursor, int n) {
    __shared__ int wsum[16];
    __shared__ int s_carry;
    const int tid = threadIdx.x;           // 1024
    const int lane = tid & 63, wid = tid >> 6;
    if (tid == 0) s_carry = 0;
    __syncthreads();
    for (int base = 0; base < n; base += 1024) {
        int i = base + tid;
        int v = (i < n) ? counts[i] : 0;
        int x = v;
#pragma unroll
        for (int o = 1; o < 64; o <<= 1) {
            int tt = __shfl_up(x, o);
            if (lane >= o) x += tt;
        }
        if (lane == 63) wsum[wid] = x;
        __syncthreads();
        if (wid == 0) {
            int ws = (lane < 16) ? wsum[lane] : 0;
#pragma unroll
            for (int o = 1; o < 16; o <<= 1) {
                int tt = __shfl_up(ws, o);
                if (lane >= o) ws += tt;
            }
            if (lane < 16) wsum[lane] = ws;   // inclusive wave-sum scan
        }
        __syncthreads();
        int wave_excl = (wid == 0) ? 0 : wsum[wid - 1];
        int carry = s_carry;
        int excl = carry + wave_excl + x - v;
        if (i < n) { row_ptr[i] = excl; cursor[i] = excl; }
        __syncthreads();
        if (tid == 1023) s_carry = carry + wsum[15];
    }
    __syncthreads();
    if (tid == 0) row_ptr[n] = s_carry;
}

// scatter with packed (edge_id, src) per slot
__global__ void scatter_pack_kernel(const int* __restrict__ src, const int* __restrict__ dst, int e,
                                    int* __restrict__ cursor, long long* __restrict__ colp) {
    int i = blockIdx.x * blockDim.x + threadIdx.x;
    if (i < e) {
        int d = dst[i];
        int p = atomicAdd(&cursor[d], 1);
        colp[p] = ((long long)i << 32) | (unsigned)src[i];
    }
}

// ============ pass A: per-edge raw attention weights (all 4 heads), no atomics ============
__global__ void alpha_kernel(const int* __restrict__ ei, const float* __restrict__ ss,
                             const float* __restrict__ sd, float* __restrict__ al, int e) {
    int i = blockIdx.x * blockDim.x + threadIdx.x;
    if (i >= e) return;
    int s = ei[i], d = ei[e + i];
    float4 svs = *(const float4*)&ss[s * 4];
    float4 svd = *(const float4*)&ss[d * 4];
    float4 dvd = *(const float4*)&sd[d * 4];
    float4 a;
    a.x = __expf(lrelu(svs.x + dvd.x) - lrelu(svd.x + dvd.x));
    a.y = __expf(lrelu(svs.y + dvd.y) - lrelu(svd.y + dvd.y));
    a.z = __expf(lrelu(svs.z + dvd.z) - lrelu(svd.z + dvd.z));
    a.w = __expf(lrelu(svs.w + dvd.w) - lrelu(svd.w + dvd.w));
    *(float4*)&al[(size_t)i * 4] = a;
}

// ============ pass B: wave per dst node; gather with precomputed alphas; denom from same loop ============
__device__ __forceinline__ void aggB(const unsigned short* __restrict__ xp,
                                     const float* __restrict__ al,
                                     const long long* __restrict__ colp,
                                     const int* __restrict__ rp,
                                     int i, int c, int hh, float& ax, float& ay) {
    const int r0 = rp[i], r1 = rp[i + 1];
    float t = 0.f, ox = 0.f, oy = 0.f;
    int k = r0;
    for (; k + 2 <= r1; k += 2) {
        long long v0 = colp[k], v1 = colp[k + 1];
        int s0 = (int)(v0 & 0xFFFFFFFFll), e0 = (int)(v0 >> 32);
        int s1 = (int)(v1 & 0xFFFFFFFFll), e1 = (int)(v1 >> 32);
        float a0 = al[(size_t)e0 * 4 + hh];
        float a1 = al[(size_t)e1 * 4 + hh];
        unsigned u0 = *(const unsigned*)&xp[(size_t)s0 * 128 + c];
        unsigned u1 = *(const unsigned*)&xp[(size_t)s1 * 128 + c];
        t += a0 + a1;
        ox += a0 * __uint_as_float(u0 << 16) + a1 * __uint_as_float(u1 << 16);
        oy += a0 * __uint_as_float(u0 & 0xFFFF0000u) + a1 * __uint_as_float(u1 & 0xFFFF0000u);
    }
    if (k < r1) {
        long long v0 = colp[k];
        int s0 = (int)(v0 & 0xFFFFFFFFll), e0 = (int)(v0 >> 32);
        float a0 = al[(size_t)e0 * 4 + hh];
        unsigned u0 = *(const unsigned*)&xp[(size_t)s0 * 128 + c];
        t += a0;
        ox += a0 * __uint_as_float(u0 << 16);
        oy += a0 * __uint_as_float(u0 & 0xFFFF0000u);
    }
    {   // self-loop: raw alpha = exp(0) = 1
        unsigned u = *(const unsigned*)&xp[(size_t)i * 128 + c];
        ox += __uint_as_float(u << 16);
        oy += __uint_as_float(u & 0xFFFF0000u);
    }
    const float id = 1.f / (t + 1.f);
    ax += id * ox;
    ay += id * oy;
}

__global__ void gat_fused_kernel(const unsigned short* __restrict__ xpO, const float* __restrict__ alO,
                                 const long long* __restrict__ cpO, const int* __restrict__ rpO,
                                 const float* __restrict__ bgO,
                                 const unsigned short* __restrict__ xpS, const float* __restrict__ alS,
                                 const long long* __restrict__ cpS, const int* __restrict__ rpS,
                                 const float* __restrict__ bgS,
                                 const float* __restrict__ emb, const float* __restrict__ Wc,
                                 const float* __restrict__ bc, float* __restrict__ out, int n) {
    const int wave = threadIdx.x >> 6, lane = threadIdx.x & 63;
    const int i = blockIdx.x * 4 + wave;
    if (i >= n) return;
    const int c = lane * 2, hh = lane >> 4;

    float ax = 0.f, ay = 0.f;
    aggB(xpO, alO, cpO, rpO, i, c, hh, ax, ay);
    aggB(xpS, alS, cpS, rpS, i, c, hh, ax, ay);

    float2 e = *(const float2*)&emb[(size_t)i * 128 + c];
    float fx = e.x + ax + bgO[c] + bgS[c];
    float fy = e.y + ay + bgO[c + 1] + bgS[c + 1];

    float2 w = *(const float2*)&Wc[c];
    float p = fx * w.x + fy * w.y;
#pragma unroll
    for (int o = 32; o > 0; o >>= 1) p += __shfl_xor(p, o);
    if (lane == 0) out[i] = 1.f / (1.f + expf(-(p + bc[0])));
}

extern "C" void kernel_launch(void* const* d_in, const int* in_sizes, int n_in,
                              void* d_out, int out_size, void* d_ws, size_t ws_size,
                              hipStream_t stream) {
    const int N = NNODES, E = NEDGES;
    const float* x_acc = (const float*)d_in[0];
    const float* x_cus = (const float*)d_in[1];
    const float* x_txn = (const float*)d_in[2];
    const int* ei_owns = (const int*)d_in[4];
    const int* ei_shr = (const int*)d_in[5];
    const float* W_acc = (const float*)d_in[6];
    const float* b_acc = (const float*)d_in[7];
    const float* W_cus = (const float*)d_in[8];
    const float* b_cus = (const float*)d_in[9];
    const float* W_txn = (const float*)d_in[10];
    const float* b_txn = (const float*)d_in[11];
    const float* Wg_o = (const float*)d_in[12];
    const float* as_o = (const float*)d_in[13];
    const float* ad_o = (const float*)d_in[14];
    const float* bg_o = (const float*)d_in[15];
    const float* Wg_s = (const float*)d_in[16];
    const float* as_s = (const float*)d_in[17];
    const float* ad_s = (const float*)d_in[18];
    const float* bg_s = (const float*)d_in[19];
    const float* W_cls = (const float*)d_in[20];
    const float* b_cls = (const float*)d_in[21];
    float* out = (float*)d_out;

    float* wf = (float*)d_ws;
    int* iw = (int*)d_ws;
    float* emb = wf;                                                // [0, 6.4M) floats
    unsigned short* xp_o = (unsigned short*)(wf + 6400000);         // 6.4M bf16
    unsigned short* xp_s = (unsigned short*)(wf + 9600000);         // 6.4M bf16
    float* ss_o = wf + 12800000;                                    // 200k
    float* sd_o = wf + 13000000;
    float* ss_s = wf + 13200000;
    float* sd_s = wf + 13400000;
    float* al_o = wf + 13600000;                                    // E*4 = 2M
    float* al_s = wf + 15600000;                                    // 2M
    int* rp_o   = iw + 17600000;                                    // N+1
    int* rp_s   = iw + 17650008;
    long long* cp_o = (long long*)(iw + 17700016);                  // E u64 (byte ofs %8==0)
    long long* cp_s = (long long*)(iw + 18700016);                  // E u64
    int* counts = iw + 19700016;                                    // N
    int* cursor = iw + 19750016;                                    // N

    const int gE = (E + 255) / 256, gN = (N + 255) / 256;
    const int gT = (N + 31) / 32;       // xp_all tiles
    const int gA = (N + 3) / 4;         // aggregate (wave per node)

    // CSR for the two live edge types (src = row 0, dst = row 1)
    zero_int<<<gN, 256, 0, stream>>>(counts, N);
    count_kernel<<<gE, 256, 0, stream>>>(ei_owns + E, E, counts);
    scan_kernel<<<1, 1024, 0, stream>>>(counts, rp_o, cursor, N);
    scatter_pack_kernel<<<gE, 256, 0, stream>>>(ei_owns, ei_owns + E, E, cursor, cp_o);
    zero_int<<<gN, 256, 0, stream>>>(counts, N);
    count_kernel<<<gE, 256, 0, stream>>>(ei_shr + E, E, counts);
    scan_kernel<<<1, 1024, 0, stream>>>(counts, rp_s, cursor, N);
    scatter_pack_kernel<<<gE, 256, 0, stream>>>(ei_shr, ei_shr + E, E, cursor, cp_s);

    // per type: fused embed+xp+scores -> edge alphas -> fused aggregate+residual+classifier
    xp_all_kernel<64><<<gT, 256, 0, stream>>>(x_acc, W_acc, b_acc, Wg_o, as_o, ad_o,
                                              Wg_s, as_s, ad_s, emb, xp_o, xp_s,
                                              ss_o, sd_o, ss_s, sd_s, N);
    alpha_kernel<<<gE, 256, 0, stream>>>(ei_owns, ss_o, sd_o, al_o, E);
    alpha_kernel<<<gE, 256, 0, stream>>>(ei_shr, ss_s, sd_s, al_s, E);
    gat_fused_kernel<<<gA, 256, 0, stream>>>(xp_o, al_o, cp_o, rp_o, bg_o,
                                             xp_s, al_s, cp_s, rp_s, bg_s,
                                             emb, W_cls, b_cls, out, N);

    xp_all_kernel<32><<<gT, 256, 0, stream>>>(x_cus, W_cus, b_cus, Wg_o, as_o, ad_o,
                                              Wg_s, as_s, ad_s, emb, xp_o, xp_s,
                                              ss_o, sd_o, ss_s, sd_s, N);
    alpha_kernel<<<gE, 256, 0, stream>>>(ei_owns, ss_o, sd_o, al_o, E);
    alpha_kernel<<<gE, 256, 0, stream>>>(ei_shr, ss_s, sd_s, al_s, E);
    gat_fused_kernel<<<gA, 256, 0, stream>>>(xp_o, al_o, cp_o, rp_o, bg_o,
                                             xp_s, al_s, cp_s, rp_s, bg_s,
                                             emb, W_cls, b_cls, out + N, N);

    xp_all_kernel<128><<<gT, 256, 0, stream>>>(x_txn, W_txn, b_txn, Wg_o, as_o, ad_o,
                                               Wg_s, as_s, ad_s, emb, xp_o, xp_s,
                                               ss_o, sd_o, ss_s, sd_s, N);
    alpha_kernel<<<gE, 256, 0, stream>>>(ei_owns, ss_o, sd_o, al_o, E);
    alpha_kernel<<<gE, 256, 0, stream>>>(ei_shr, ss_s, sd_s, al_s, E);
    gat_fused_kernel<<<gA, 256, 0, stream>>>(xp_o, al_o, cp_o, rp_o, bg_o,
                                             xp_s, al_s, cp_s, rp_s, bg_s,
                                             emb, W_cls, b_cls, out + 2 * N, N);
}